// Round 10
// baseline (286.344 us; speedup 1.0000x reference)
//
#include <hip/hip_runtime.h>

#define N0 6400
#define NC 256
#define WW 80

using half8   = __attribute__((ext_vector_type(8))) _Float16;
using floatx4 = __attribute__((ext_vector_type(4))) float;
#define GLOBAL_AS __attribute__((address_space(1)))
#define LDS_AS    __attribute__((address_space(3)))

__device__ __forceinline__ unsigned long long packvi(float v, int i) {
    return ((unsigned long long)__float_as_uint(v) << 32) | (unsigned int)i;
}

// ------ K1: fused norm + transpose (C,N)->(N,256) fp16, y selects f0/f1
// One block = 32 points x all 256 channels: load to LDS, compute the 32
// inverse norms in-block (8-lane butterfly), write normalized fp16.
__global__ __launch_bounds__(256) void ktransN(const float* __restrict__ f0,
                                               const float* __restrict__ f1,
                                               _Float16* __restrict__ A2,
                                               _Float16* __restrict__ B2) {
    __shared__ float tile[256][33];                  // 33.8 KB
    const float* src = blockIdx.y ? f1 : f0;
    _Float16* dst    = blockIdx.y ? B2 : A2;
    int t = threadIdx.x;
    int n0 = blockIdx.x * 32;
    int tx = t & 31, ty = t >> 5;                    // 32 x 8
#pragma unroll
    for (int u = 0; u < 32; ++u)
        tile[ty + u * 8][tx] = src[(ty + u * 8) * N0 + n0 + tx];
    __syncthreads();
    int n = t >> 3;                                  // 0..31 local point
    int part = t & 7;                                // 0..7 channel slice
    float s = 0.f;
#pragma unroll
    for (int c0 = 0; c0 < 32; ++c0) {                // c = part + 8*c0 (bank-spread)
        float v = tile[c0 * 8 + part][n];
        s += v * v;
    }
    s += __shfl_xor(s, 1);                           // butterfly within 8-lane group
    s += __shfl_xor(s, 2);
    s += __shfl_xor(s, 4);
    float iv = 1.0f / fmaxf(sqrtf(s), 1e-12f);
#pragma unroll
    for (int u = 0; u < 8; ++u) {                    // 32 channels/thread
        int c = u * 32 + part * 4;
        union { ushort4 u4; _Float16 h[4]; } pk;
#pragma unroll
        for (int w = 0; w < 4; ++w)
            pk.h[w] = (_Float16)(tile[c + w][n] * iv);
        *(ushort4*)&dst[(n0 + n) * NC + c] = pk.u4;
    }
}

// -------- staging: 128 rows x 256 k (full-K, 64 KiB), 512 threads -------
// LDS layout [kk(4)][row(128)][64 halves]; 16B chunk at (chunk ^ (row&7)),
// swizzle applied to the GLOBAL source so LDS dest stays lane-linear.
__device__ __forceinline__ void stage_full(const _Float16* __restrict__ G,
                                           unsigned short* lds, int r0, int tid) {
    int rl = tid >> 3;                               // 0..63
    int ch = ((tid & 7) ^ (rl & 7)) * 8;             // swizzled chunk (halves)
#pragma unroll
    for (int kk = 0; kk < 4; ++kk)
#pragma unroll
        for (int g = 0; g < 2; ++g) {
            const _Float16* ga = G + (r0 + g * 64 + rl) * NC + kk * 64 + ch;
            __builtin_amdgcn_global_load_lds((const GLOBAL_AS unsigned int*)ga,
                (LDS_AS unsigned int*)&lds[kk * 8192 + g * 4096 + tid * 8], 16, 0, 0);
        }
}

// -------- full-K compute, SWAPPED operands: acc = mfma(bf, af) ---------
// D: lane&15 -> P row (af rows), (lane>>4)*4+reg -> P col (bf rows).
__device__ __forceinline__ void compute_tile(const unsigned short* cur,
                                             const half8 af[4][8],
                                             int lane, int wn,
                                             floatx4 acc[4][2]) {
    int q = lane >> 4;
    int rb0 = wn * 32 + (lane & 15), rb1 = rb0 + 16;
#pragma unroll
    for (int s = 0; s < 8; ++s) {
        int c = s * 4 + q, kk = c >> 3, cq = c & 7;
        half8 bf0 = *(const half8*)&cur[kk * 8192 + rb0 * 64 + ((cq ^ (rb0 & 7)) * 8)];
        half8 bf1 = *(const half8*)&cur[kk * 8192 + rb1 * 64 + ((cq ^ (rb1 & 7)) * 8)];
#pragma unroll
        for (int at = 0; at < 4; ++at) {
            acc[at][0] = __builtin_amdgcn_mfma_f32_16x16x32_f16(bf0, af[at][s], acc[at][0], 0, 0, 0);
            acc[at][1] = __builtin_amdgcn_mfma_f32_16x16x32_f16(bf1, af[at][s], acc[at][1], 0, 0, 0);
        }
    }
}

// -------- shared prologue: A panel -> regs, first B tile staged --------
__device__ __forceinline__ void gemm_prologue(const _Float16* __restrict__ A2,
                                              const _Float16* __restrict__ B2,
                                              unsigned short* lds,
                                              int i0, int jp, int tid, int lane,
                                              int wm, half8 af[4][8]) {
    int q = lane >> 4;
    stage_full(A2, lds, i0, tid);                    // A -> lo half
    __syncthreads();
#pragma unroll
    for (int at = 0; at < 4; ++at)
#pragma unroll
        for (int s = 0; s < 8; ++s) {
            int c = s * 4 + q, kk = c >> 3, cq = c & 7;
            int ra = wm * 64 + at * 16 + (lane & 15);
            af[at][s] = *(const half8*)&lds[kk * 8192 + ra * 64 + ((cq ^ (ra & 7)) * 8)];
        }
    stage_full(B2, lds + 32768, jp, tid);            // B tile 0 -> hi half
    __syncthreads();                                 // af in regs; B0 ready
}

// ---------------- K2: GEMM pass 1 — row/col partial sums ----------------
// Grid (50,5), 512 thr, 1 block/CU, 128 KiB LDS, B double-buffered with
// stage-ahead; ONE barrier per j-tile. Partials to per-wave global slots.
__global__ __launch_bounds__(512, 2) void kgemm1N(const _Float16* __restrict__ A2,
                                                  const _Float16* __restrict__ B2,
                                                  float* __restrict__ rowpart,
                                                  float* __restrict__ colpart) {
    __shared__ __align__(16) unsigned short lds[65536];   // 128 KiB
    int tid = threadIdx.x, lane = tid & 63, wave = tid >> 6;
    int wm = wave & 1, wn = wave >> 1, q = lane >> 4;
    int i0 = blockIdx.x * 128, jp = blockIdx.y * 1280;

    half8 af[4][8];
    gemm_prologue(A2, B2, lds, i0, jp, tid, lane, wm, af);

    float rsum[4] = {0.f, 0.f, 0.f, 0.f};
    for (int jt = 0; jt < 10; ++jt) {
        unsigned short* cur = lds + ((jt & 1) ? 0 : 32768);
        if (jt < 9)                                  // stage-ahead, other buf
            stage_full(B2, lds + ((jt & 1) ? 32768 : 0), jp + (jt + 1) * 128, tid);

        floatx4 acc[4][2] = {};
        compute_tile(cur, af, lane, wn, acc);

        int jcb = jp + jt * 128;
        float csum[2][4] = {};
#pragma unroll
        for (int at = 0; at < 4; ++at)
#pragma unroll
            for (int bt = 0; bt < 2; ++bt)
#pragma unroll
                for (int r = 0; r < 4; ++r) {
                    float e = __expf(10.0f * acc[at][bt][r]);
                    rsum[at] += e;                   // row = at*16+(lane&15)
                    csum[bt][r] += e;                // col = wn*32+bt*16+q*4+r
                }
#pragma unroll
        for (int bt = 0; bt < 2; ++bt)
#pragma unroll
            for (int r = 0; r < 4; ++r) {
                float v = csum[bt][r];
                v += __shfl_xor(v, 1);
                v += __shfl_xor(v, 2);
                v += __shfl_xor(v, 4);
                v += __shfl_xor(v, 8);
                if ((lane & 15) == 0)
                    colpart[(blockIdx.x * 2 + wm) * N0 + jcb + wn * 32 + bt * 16 + q * 4 + r] = v;
            }
        __syncthreads();                             // cur reads done + stage drained
    }
#pragma unroll
    for (int at = 0; at < 4; ++at) {
        float v = rsum[at];
        v += __shfl_xor(v, 16);
        v += __shfl_xor(v, 32);
        if (lane < 16)
            rowpart[(blockIdx.y * 4 + wn) * N0 + i0 + wm * 64 + at * 16 + lane] = v;
    }
}

// ---------------- K2.5: fold partials into rowsum / colsum --------------
__global__ __launch_bounds__(256) void kreduce(const float* __restrict__ rowpart,
                                               const float* __restrict__ colpart,
                                               float* __restrict__ rowsum,
                                               float* __restrict__ colsum) {
    int t = blockIdx.x * 256 + threadIdx.x;          // 0..12799
    if (t < N0) {
        float s = 0.f;
#pragma unroll
        for (int k = 0; k < 20; ++k) s += rowpart[k * N0 + t];
        rowsum[t] = s;
    } else {
        int j = t - N0;
        float s = 0.f;
        for (int k = 0; k < 100; ++k) s += colpart[k * N0 + j];
        colsum[j] = s;
    }
}

// ---------------- K3: GEMM pass 2 — direct P stores + log argmax --------
__global__ __launch_bounds__(512, 2) void kgemm2N(const _Float16* __restrict__ A2,
                                                  const _Float16* __restrict__ B2,
                                                  const float* __restrict__ rowsum,
                                                  const float* __restrict__ colsum,
                                                  float* __restrict__ P,
                                                  unsigned long long* __restrict__ rowbpart,
                                                  unsigned long long* __restrict__ colbpart) {
    __shared__ __align__(16) unsigned short lds[65536];   // 128 KiB
    int tid = threadIdx.x, lane = tid & 63, wave = tid >> 6;
    int wm = wave & 1, wn = wave >> 1, q = lane >> 4;
    int i0 = blockIdx.x * 128, jp = blockIdx.y * 1280;

    half8 af[4][8];
    gemm_prologue(A2, B2, lds, i0, jp, tid, lane, wm, af);

    float ir[4], lr[4];                              // per-lane row (lane&15)
#pragma unroll
    for (int at = 0; at < 4; ++at) {
        ir[at] = 1.0f / rowsum[i0 + wm * 64 + at * 16 + (lane & 15)];
        lr[at] = __logf(ir[at]) * 0.05f + 4.0f;      // ln(ir)/20 + bias
    }

    unsigned long long rbv[4] = {};                  // row argmax (log-domain)
    for (int jt = 0; jt < 10; ++jt) {
        unsigned short* cur = lds + ((jt & 1) ? 0 : 32768);
        if (jt < 9)
            stage_full(B2, lds + ((jt & 1) ? 32768 : 0), jp + (jt + 1) * 128, tid);

        floatx4 acc[4][2] = {};
        compute_tile(cur, af, lane, wn, acc);

        int jcb = jp + jt * 128;
        float ic[2][4], lc[2][4];
#pragma unroll
        for (int bt = 0; bt < 2; ++bt) {
            float4 c4 = *(const float4*)&colsum[jcb + wn * 32 + bt * 16 + q * 4];
            ic[bt][0] = 1.0f / c4.x; ic[bt][1] = 1.0f / c4.y;
            ic[bt][2] = 1.0f / c4.z; ic[bt][3] = 1.0f / c4.w;
#pragma unroll
            for (int r = 0; r < 4; ++r)
                lc[bt][r] = __logf(ic[bt][r]) * 0.05f + 4.0f;
        }

        unsigned long long colb[2][4] = {};
#pragma unroll
        for (int at = 0; at < 4; ++at) {
            int row = i0 + wm * 64 + at * 16 + (lane & 15);
#pragma unroll
            for (int bt = 0; bt < 2; ++bt) {
                floatx4 pv;
#pragma unroll
                for (int r = 0; r < 4; ++r) {
                    float a = acc[at][bt][r];
                    pv[r] = __expf(20.0f * a) * ir[at] * ic[bt][r];
                    unsigned long long pr = packvi(a + lc[bt][r],
                                                   jcb + wn * 32 + bt * 16 + q * 4 + r);
                    if (pr > rbv[at]) rbv[at] = pr;
                    unsigned long long pc = packvi(a + lr[at], row);
                    if (pc > colb[bt][r]) colb[bt][r] = pc;
                }
                __builtin_nontemporal_store(pv,
                    (floatx4*)&P[row * N0 + jcb + wn * 32 + bt * 16 + q * 4]);
            }
        }
#pragma unroll
        for (int bt = 0; bt < 2; ++bt)
#pragma unroll
            for (int r = 0; r < 4; ++r) {
                unsigned long long v = colb[bt][r];
#pragma unroll
                for (int s = 1; s < 16; s <<= 1) {
                    unsigned long long o = __shfl_xor(v, s);
                    if (o > v) v = o;
                }
                if ((lane & 15) == 0)
                    colbpart[(blockIdx.x * 2 + wm) * N0 + jcb + wn * 32 + bt * 16 + q * 4 + r] = v;
            }
        __syncthreads();
    }
#pragma unroll
    for (int at = 0; at < 4; ++at) {
        unsigned long long v = rbv[at];
        unsigned long long o = __shfl_xor(v, 16);
        if (o > v) v = o;
        o = __shfl_xor(v, 32);
        if (o > v) v = o;
        if (lane < 16)
            rowbpart[(blockIdx.y * 4 + wn) * N0 + i0 + wm * 64 + at * 16 + lane] = v;
    }
}

// ---------------- K4: fold argmax partials + mutual-NN outputs ----------
__global__ __launch_bounds__(256) void kmatch(const unsigned long long* __restrict__ rowbpart,
                                              const unsigned long long* __restrict__ colbpart,
                                              const float* __restrict__ P,
                                              float* __restrict__ out) {
    int i = blockIdx.x * 256 + threadIdx.x;      // 0..6399
    unsigned long long rb = 0ull;
#pragma unroll
    for (int k = 0; k < 20; ++k) {
        unsigned long long v = rowbpart[k * N0 + i];
        if (v > rb) rb = v;
    }
    int jj = (int)(rb & 0xffffffffu);
    unsigned long long cb = 0ull;
#pragma unroll 4
    for (int k = 0; k < 100; ++k) {
        unsigned long long v = colbpart[k * N0 + jj];
        if (v > cb) cb = v;
    }
    int i2 = (int)(cb & 0xffffffffu);
    float conf = P[i * N0 + jj];                 // recover max P value
    bool valid = (i2 == i) && (conf > 0.2f);
    float vf = valid ? 1.0f : 0.0f;

    float* mk0   = out + 40960000;
    float* mk1   = out + 40972800;
    float* mconf = out + 40985600;
    float* vout  = out + 40992000;
    mk0[i * 2 + 0] = vf * (float)(i % WW);
    mk0[i * 2 + 1] = vf * (float)(i / WW);
    mk1[i * 2 + 0] = vf * (float)(jj % WW);
    mk1[i * 2 + 1] = vf * (float)(jj / WW);
    mconf[i] = valid ? conf : 0.0f;
    vout[i]  = vf;
}

extern "C" void kernel_launch(void* const* d_in, const int* in_sizes, int n_in,
                              void* d_out, int out_size, void* d_ws, size_t ws_size,
                              hipStream_t stream) {
    const float* f0 = (const float*)d_in[0];
    const float* f1 = (const float*)d_in[1];
    float* out = (float*)d_out;

    _Float16* A2 = (_Float16*)d_ws;                  // 6400x256 fp16
    _Float16* B2 = A2 + 6400 * 256;
    // u64 region (8B-aligned: 6,553,600 % 8 == 0)
    unsigned long long* rowbpart = (unsigned long long*)(B2 + 6400 * 256); // 20x6400
    unsigned long long* colbpart = rowbpart + 20 * 6400;                   // 100x6400
    // f32 region
    float* rowsum  = (float*)(colbpart + 100 * 6400);  // 6400
    float* colsum  = rowsum + 6400;                    // 6400
    float* rowpart = colsum + 6400;                    // 20 x 6400
    float* colpart = rowpart + 20 * 6400;              // 100 x 6400

    ktransN<<<dim3(200, 2), 256, 0, stream>>>(f0, f1, A2, B2);
    kgemm1N<<<dim3(50, 5), 512, 0, stream>>>(A2, B2, rowpart, colpart);
    kreduce<<<50, 256, 0, stream>>>(rowpart, colpart, rowsum, colsum);
    kgemm2N<<<dim3(50, 5), 512, 0, stream>>>(A2, B2, rowsum, colsum,
                                             out, rowbpart, colbpart);
    kmatch<<<25, 256, 0, stream>>>(rowbpart, colbpart, out, out);
}